// Round 3
// baseline (3574.525 us; speedup 1.0000x reference)
//
#include <hip/hip_runtime.h>
#include <cstdint>

#define B_ 2048
#define T_ 200
#define E_ 128
#define H_ 128

__device__ __forceinline__ float sigmoidf_(float x) { return 1.0f / (1.0f + __expf(-x)); }
__device__ __forceinline__ float tanhf_(float x) {
  float e = __expf(2.0f * x);
  return 1.0f - 2.0f / (e + 1.0f);
}

// K0: fold att_W1 [512,80] into Wq=W1a+W1c, Wf=W1b-W1c, Wp=W1d  (each [128,80])
__global__ void fold_w1_kernel(const float* __restrict__ W1, float* __restrict__ Wq,
                               float* __restrict__ Wf, float* __restrict__ Wp) {
  int idx = blockIdx.x * blockDim.x + threadIdx.x;
  if (idx >= 128 * 80) return;
  int k = idx / 80, n = idx % 80;
  float a = W1[k * 80 + n];
  float b = W1[(128 + k) * 80 + n];
  float c = W1[(256 + k) * 80 + n];
  float d = W1[(384 + k) * 80 + n];
  Wq[idx] = a + c;
  Wf[idx] = b - c;
  Wp[idx] = d;
}

// K1: q = PReLU(item @ att_Wi + bi); qW = q @ Wq  (t-invariant part of attention layer 1)
__global__ __launch_bounds__(128) void q_kernel(const float* __restrict__ item,
    const float* __restrict__ Wi, const float* __restrict__ bi, const float* __restrict__ alpha,
    const float* __restrict__ Wq, float* __restrict__ q, float* __restrict__ qW) {
  __shared__ float it[128];
  __shared__ float qs[128];
  const int b = blockIdx.x, n = threadIdx.x;
  it[n] = item[b * 128 + n];
  __syncthreads();
  float acc = bi[n];
  #pragma unroll 8
  for (int k = 0; k < 128; ++k) acc = fmaf(it[k], Wi[k * 128 + n], acc);
  acc = acc >= 0.f ? acc : alpha[n] * acc;
  qs[n] = acc;
  q[b * 128 + n] = acc;
  __syncthreads();
  if (n < 80) {
    float a2 = 0.f;
    #pragma unroll 8
    for (int k = 0; k < 128; ++k) a2 = fmaf(qs[k], Wq[k * 80 + n], a2);
    qW[b * 80 + n] = a2;
  }
}

// K2/K5: fused (x@W + h@U) recurrence, REGISTER-RESIDENT weights.
// 4 batch rows per block; h lives in LDS across all 200 steps (rows independent ->
// no grid sync). 512 threads = 128 cols x {mat: W|U} x {k-half: 0|1}. Each thread
// holds a 64k x 3col weight slice (192 VGPRs, loaded ONCE) -> zero per-step weight
// traffic. acc is only [4][3] (vs [8][3] in the 8-row variant) to stay safely
// under the 256-VGPR cap of launch_bounds(512,2). Phase-A state reads are
// wave-broadcast float4 (ds_read_b128): 4 LDS reads per 48 FMAs -> VALU-bound.
// Next-x is prefetched into a REGISTER at the top of the step (T14 split) and
// committed to LDS in phase B, hiding HBM latency under phase A.
template<bool AUGRU>
__global__ __launch_bounds__(512, 2) void scan_kernel(
    const float* __restrict__ seqb, const float* __restrict__ Wm, const float* __restrict__ Um,
    const float* __restrict__ bx, const float* __restrict__ bh,
    const float* __restrict__ attp, float* __restrict__ outp) {
  __shared__ float xt[4][128];
  __shared__ float hb[4][128];
  __shared__ float pp[4][4][384];   // [grp = mat*2+kg][row][gatecol]
  __shared__ float atts[4][200];
  const int tid = threadIdx.x;
  const int b0 = blockIdx.x * 4;
  const int c = tid & 127;
  const int grp = tid >> 7;   // 0..3 (wave-aligned: each wave entirely in one grp)
  const int mat = grp >> 1;   // 0: x@W, 1: h@U
  const int kg = grp & 1;     // k-half
  const int kbase = kg * 64;
  const int r_pre = tid >> 7;   // prefetch mapping: 4 rows x 128 cols
  const int k_pre = tid & 127;

  // ---- load this thread's weight slice into registers (compile-time indexed) ----
  const float* WU = (mat ? Um : Wm) + (size_t)kbase * 384 + c;
  float w[64][3];
  #pragma unroll
  for (int kk = 0; kk < 64; ++kk) {
    #pragma unroll
    for (int j = 0; j < 3; ++j) w[kk][j] = WU[(size_t)kk * 384 + j * 128];
  }
  // bias baked into kg==0 partial's accumulator init
  float bias0 = 0.f, bias1 = 0.f, bias2 = 0.f;
  if (kg == 0) {
    const float* bb = mat ? bh : bx;
    bias0 = bb[c]; bias1 = bb[c + 128]; bias2 = bb[c + 256];
  }
  const float* S = (mat ? &hb[0][0] : &xt[0][0]) + kbase;

  for (int i = tid; i < 512; i += 512) {
    int r = i >> 7, k = i & 127;
    hb[r][k] = 0.f;
    xt[r][k] = seqb[(size_t)(b0 + r) * (T_ * 128) + k];  // t = 0
  }
  if (AUGRU) {
    for (int i = tid; i < 4 * 200; i += 512)
      atts[i / 200][i % 200] = attp[(size_t)(b0 + i / 200) * T_ + (i % 200)];
  }
  __syncthreads();

  for (int t = 0; t < T_; ++t) {
    // T14: issue next-x load NOW; ~3000 cyc of phase A hides the HBM latency.
    float xn = 0.f;
    if (t + 1 < T_)
      xn = seqb[(size_t)(b0 + r_pre) * (T_ * 128) + (size_t)(t + 1) * 128 + k_pre];

    // ---- phase A: partial pre-activations over this thread's 64-k slice ----
    float a0[3], a1[3], a2[3], a3[3];
    #pragma unroll
    for (int j = 0; j < 3; ++j) { a0[j] = bias0; a1[j] = 0.f; a2[j] = 0.f; a3[j] = 0.f; }
    a0[0] = bias0; a0[1] = bias1; a0[2] = bias2;
    #pragma unroll
    for (int k4 = 0; k4 < 16; ++k4) {
      float4 s0 = *(const float4*)&S[0 * 128 + k4 * 4];
      float4 s1 = *(const float4*)&S[1 * 128 + k4 * 4];
      float4 s2 = *(const float4*)&S[2 * 128 + k4 * 4];
      float4 s3 = *(const float4*)&S[3 * 128 + k4 * 4];
      #pragma unroll
      for (int u = 0; u < 4; ++u) {
        const float e0 = (&s0.x)[u], e1 = (&s1.x)[u], e2 = (&s2.x)[u], e3 = (&s3.x)[u];
        #pragma unroll
        for (int j = 0; j < 3; ++j) {
          const float wj = w[k4 * 4 + u][j];
          a0[j] = fmaf(e0, wj, a0[j]);
          a1[j] = fmaf(e1, wj, a1[j]);
          a2[j] = fmaf(e2, wj, a2[j]);
          a3[j] = fmaf(e3, wj, a3[j]);
        }
      }
    }
    {
      float* od = &pp[grp][0][0] + c;
      #pragma unroll
      for (int j = 0; j < 3; ++j) {
        od[0 * 384 + j * 128] = a0[j];
        od[1 * 384 + j * 128] = a1[j];
        od[2 * 384 + j * 128] = a2[j];
        od[3 * 384 + j * 128] = a3[j];
      }
    }
    __syncthreads();
    // ---- phase B: reduce k-half partials, gates, h update (+ feats store) ----
    {
      const int r = tid >> 7, j = tid & 127;
      float pxz = pp[0][r][j]       + pp[1][r][j];
      float pxr = pp[0][r][j + 128] + pp[1][r][j + 128];
      float pxc = pp[0][r][j + 256] + pp[1][r][j + 256];
      float phz = pp[2][r][j]       + pp[3][r][j];
      float phr = pp[2][r][j + 128] + pp[3][r][j + 128];
      float phc = pp[2][r][j + 256] + pp[3][r][j + 256];
      float z = sigmoidf_(pxz + phz);
      float rr = sigmoidf_(pxr + phr);
      float cc = tanhf_(fmaf(rr, phc, pxc));
      float hold = hb[r][j];
      float hn;
      if (AUGRU) {
        float u = atts[r][t] * z;
        hn = (1.f - u) * hold + u * cc;
      } else {
        hn = z * hold + (1.f - z) * cc;
        outp[(size_t)(b0 + r) * (T_ * 128) + (size_t)t * 128 + j] = hn;
      }
      hb[r][j] = hn;
      if (t + 1 < T_) xt[r_pre][k_pre] = xn;  // commit prefetched x (r_pre==r, k_pre==j)
    }
    __syncthreads();
  }
  if (AUGRU) {
    const int r = tid >> 7, j = tid & 127;
    outp[(size_t)(b0 + r) * 128 + j] = hb[r][j];
  }
}

// K3: attention scores. Per (b, 64-t tile): layer1 (folded weights, k=128 over f
// and q*f), sigmoid; layer2 80->40 sigmoid; layer3 40->1.
__global__ __launch_bounds__(256) void attn_kernel(
    const float* __restrict__ feats, const float* __restrict__ qv, const float* __restrict__ qWv,
    const float* __restrict__ Wf, const float* __restrict__ Wp, const float* __restrict__ b1,
    const float* __restrict__ W2, const float* __restrict__ b2,
    const float* __restrict__ W3, const float* __restrict__ b3,
    float* __restrict__ scores) {
  __shared__ float fs[64][128];
  __shared__ float gs[64][128];
  __shared__ float qs[128];
  __shared__ float h1[64][80];
  __shared__ float h2[64][40];
  const int b = blockIdx.x;
  const int t0 = blockIdx.y * 64;
  const int P = min(64, T_ - t0);
  const int tid = threadIdx.x;
  if (tid < 128) qs[tid] = qv[b * 128 + tid];
  __syncthreads();
  for (int i = tid; i < P * 128; i += 256) {
    int p = i >> 7, k = i & 127;
    float f = feats[(size_t)b * (T_ * 128) + (size_t)(t0 + p) * 128 + k];
    fs[p][k] = f;
    gs[p][k] = f * qs[k];
  }
  __syncthreads();
  // layer 1: register tile 4 positions x 5 neurons per thread
  {
    const int ng = (tid & 15) * 5;
    const int pg = (tid >> 4) * 4;
    float acc[4][5];
    #pragma unroll
    for (int pi = 0; pi < 4; ++pi)
      #pragma unroll
      for (int nj = 0; nj < 5; ++nj) acc[pi][nj] = 0.f;
    for (int k = 0; k < 128; ++k) {
      float wf[5], wp[5];
      #pragma unroll
      for (int nj = 0; nj < 5; ++nj) {
        wf[nj] = Wf[k * 80 + ng + nj];
        wp[nj] = Wp[k * 80 + ng + nj];
      }
      #pragma unroll
      for (int pi = 0; pi < 4; ++pi) {
        float f = fs[pg + pi][k];
        float g = gs[pg + pi][k];
        #pragma unroll
        for (int nj = 0; nj < 5; ++nj) acc[pi][nj] = fmaf(f, wf[nj], fmaf(g, wp[nj], acc[pi][nj]));
      }
    }
    #pragma unroll
    for (int pi = 0; pi < 4; ++pi) {
      int p = pg + pi;
      if (p < P) {
        #pragma unroll
        for (int nj = 0; nj < 5; ++nj) {
          int n = ng + nj;
          h1[p][n] = sigmoidf_(acc[pi][nj] + qWv[b * 80 + n] + b1[n]);
        }
      }
    }
  }
  __syncthreads();
  // layer 2
  for (int i = tid; i < P * 40; i += 256) {
    int p = i / 40, n = i - p * 40;
    float acc = b2[n];
    #pragma unroll 8
    for (int k = 0; k < 80; ++k) acc = fmaf(h1[p][k], W2[k * 40 + n], acc);
    h2[p][n] = sigmoidf_(acc);
  }
  __syncthreads();
  // layer 3
  if (tid < P) {
    float acc = b3[0];
    #pragma unroll
    for (int k = 0; k < 40; ++k) acc = fmaf(h2[tid][k], W3[k], acc);
    scores[(size_t)b * T_ + t0 + tid] = acc;
  }
}

// K4: masked softmax over T per batch row (in place). Replicates jnp.where(mask==1, s, finfo.min).
__global__ __launch_bounds__(64) void softmax_kernel(float* __restrict__ att, const int* __restrict__ mask) {
  const int b = blockIdx.x;
  const int lane = threadIdx.x;
  const float NEG = -3.402823466e38f;
  float v[4];
  float m = NEG;
  #pragma unroll
  for (int i = 0; i < 4; ++i) {
    int t = lane + i * 64;
    if (t < T_) {
      float s = att[(size_t)b * T_ + t];
      v[i] = (mask[(size_t)b * T_ + t] == 1) ? s : NEG;
      m = fmaxf(m, v[i]);
    } else {
      v[i] = NEG;
    }
  }
  #pragma unroll
  for (int off = 32; off > 0; off >>= 1) m = fmaxf(m, __shfl_xor(m, off));
  float s = 0.f;
  #pragma unroll
  for (int i = 0; i < 4; ++i) {
    int t = lane + i * 64;
    if (t < T_) {
      v[i] = __expf(v[i] - m);
      s += v[i];
    }
  }
  #pragma unroll
  for (int off = 32; off > 0; off >>= 1) s += __shfl_xor(s, off);
  float inv = 1.0f / s;
  #pragma unroll
  for (int i = 0; i < 4; ++i) {
    int t = lane + i * 64;
    if (t < T_) att[(size_t)b * T_ + t] = v[i] * inv;
  }
}

extern "C" void kernel_launch(void* const* d_in, const int* in_sizes, int n_in,
                              void* d_out, int out_size, void* d_ws, size_t ws_size,
                              hipStream_t stream) {
  const float* item     = (const float*)d_in[0];
  const float* seq      = (const float*)d_in[1];
  const int*   mask     = (const int*)d_in[2];
  const float* gru_W    = (const float*)d_in[3];
  const float* gru_U    = (const float*)d_in[4];
  const float* gru_bx   = (const float*)d_in[5];
  const float* gru_bh   = (const float*)d_in[6];
  const float* att_Wi   = (const float*)d_in[7];
  const float* att_bi   = (const float*)d_in[8];
  const float* att_al   = (const float*)d_in[9];
  const float* att_W1   = (const float*)d_in[10];
  const float* att_b1   = (const float*)d_in[11];
  const float* att_W2   = (const float*)d_in[12];
  const float* att_b2   = (const float*)d_in[13];
  const float* att_W3   = (const float*)d_in[14];
  const float* att_b3   = (const float*)d_in[15];
  const float* aug_W    = (const float*)d_in[16];
  const float* aug_U    = (const float*)d_in[17];
  const float* aug_bx   = (const float*)d_in[18];
  const float* aug_bh   = (const float*)d_in[19];

  float* out = (float*)d_out;
  float* final_out = out;                  // [B,128]  (return order: final, feats)
  float* feats = out + (size_t)B_ * H_;    // [B,T,128]

  // workspace layout (floats); total ~3.5 MB
  float* ws = (float*)d_ws;
  float* q   = ws;                          // B*128
  float* qW  = q + (size_t)B_ * 128;        // B*80
  float* att = qW + (size_t)B_ * 80;        // B*T (scores -> probs, in place)
  float* Wq  = att + (size_t)B_ * T_;       // 128*80
  float* Wf  = Wq + 128 * 80;               // 128*80
  float* Wp  = Wf + 128 * 80;               // 128*80

  fold_w1_kernel<<<40, 256, 0, stream>>>(att_W1, Wq, Wf, Wp);
  q_kernel<<<B_, 128, 0, stream>>>(item, att_Wi, att_bi, att_al, Wq, q, qW);
  scan_kernel<false><<<B_ / 4, 512, 0, stream>>>(seq, gru_W, gru_U, gru_bx, gru_bh, nullptr, feats);
  attn_kernel<<<dim3(B_, 4), 256, 0, stream>>>(feats, q, qW, Wf, Wp, att_b1, att_W2, att_b2,
                                               att_W3, att_b3, att);
  softmax_kernel<<<B_, 64, 0, stream>>>(att, mask);
  scan_kernel<true><<<B_ / 4, 512, 0, stream>>>(feats, aug_W, aug_U, aug_bx, aug_bh, att, final_out);
}